// Round 13
// baseline (253.956 us; speedup 1.0000x reference)
//
#include <hip/hip_runtime.h>
#include <hip/hip_bf16.h>
#include <cstdint>
#include <cstddef>

// ---------------------------------------------------------------------------
// Self-attention, B=4 S=2048 D=1024. Inputs FLOAT32, output FLOAT32.
//   Q = x@Wq^T+bq ; K = x@Wk^T+bk ; V = x@Wv^T+bv
//   S = Q@K^T ; P = softmax(S)*(1/32) ; O = P@V
// FP16 pipeline (calibrated: absmax 4.88e-4 vs threshold 1.758e-3).
// Round-13 deltas vs round 12 (240.2 us):
//   * softmax 4 rows/block (barrier/reduction amortized 4x; was ~16 us for
//     96 MB, HBM floor ~15).
//   * split 2 rows/block (tensor boundaries all even -> no straddle).
//   * nontemporal: Sc stores (scores) + Sc loads (softmax) are zero-reuse
//     streams -> keep Qp/Kp/P resident in L2; pv out stores nt (protects P).
//   GEMMs untouched: all three sit at the m97 structural plateau (~888 TF,
//   MfmaUtil 38%, FETCH = unique bytes after round-12 XCD swizzle); m131-141
//   evidence says source-level K-loop tweaks are neutral there.
// Workspace (peak 150,994,944 B):
//   Qp [8192][1024] f16 @ 0     (16 MB)
//   Kp [8192][1024] f16 @ 16M   (16 MB)
//   Vt [4][1024][2048]  @ 32M   (16 MB)  V^T per batch, f16
//   Sc [4][2048][2048]  @ 48M   (64 MB)  f32 scores
//   P  [4][2048][2048]  @ 112M  (32 MB)  f16 probs
//   xh [8192][1024] f16 @ 48M   (16 MB)  aliases Sc (dead after qkv)
//   Wh 3x[1024][1024]   @ 64M   ( 6 MB)  aliases Sc (dead after qkv)
// ---------------------------------------------------------------------------

typedef __attribute__((ext_vector_type(8))) _Float16 f16x8;
typedef __attribute__((ext_vector_type(4))) _Float16 f16x4;
typedef __attribute__((ext_vector_type(4))) float f32x4;

#define BM 128
#define BN 128
#define BK 64

#define NBATCH 4
#define SEQ 2048
#define DIM 1024
#define MTOT (NBATCH * SEQ)   // 8192

__device__ __forceinline__ void async_ld16(const void* g, void* l) {
  __builtin_amdgcn_global_load_lds((__attribute__((address_space(1))) void*)(g),
                                   (__attribute__((address_space(3))) void*)(l),
                                   16, 0, 0);
}

// C[m0..+127][n0..+127] += A[m,k] * B[n,k]  (row-major, B^T GEMM)
// A,B f16; async global->LDS staging (XOR-swizzled slots); 4 waves 2x2;
// each wave 64x64 via 4x4 of 16x16x32 f16 MFMA.
__device__ __forceinline__ void gemm_core(const _Float16* __restrict__ A, int lda,
                                          const _Float16* __restrict__ B, int ldb,
                                          int K, int m0, int n0,
                                          _Float16* As, _Float16* Bs,
                                          f32x4 (&acc)[4][4]) {
  const int t = threadIdx.x;
  const int w = t >> 6;
  const int lrow = t & 15;
  const int quad = (t >> 4) & 3;
  const int wm = (w >> 1) << 6;
  const int wn = (w & 1) << 6;

  // Staging: thread t covers tile row rb (+32 per i), global colblock
  // (t&7)^(rb&7) (XOR swizzle; LDS dest is the wave-contiguous slot t&7).
  const int rb = t >> 3;                               // 0..31
  const int co = (((t & 7) ^ (rb & 7)) << 3);          // swizzled source col
  const _Float16* Ap = A + (size_t)(m0 + rb) * lda + co;
  const _Float16* Bp = B + (size_t)(n0 + rb) * ldb + co;

  const int sw = lrow & 7;  // row-phase for read-side swizzle

  for (int k0 = 0; k0 < K; k0 += BK) {
#pragma unroll
    for (int i = 0; i < 4; ++i)
      async_ld16(Ap + (size_t)(i * 32) * lda + k0, As + i * 2048 + (w << 9));
#pragma unroll
    for (int i = 0; i < 4; ++i)
      async_ld16(Bp + (size_t)(i * 32) * ldb + k0, Bs + i * 2048 + (w << 9));
    __syncthreads();
#pragma unroll
    for (int kk = 0; kk < BK; kk += 32) {
      const int slot = ((kk >> 3) + quad) ^ sw;  // swizzled 8-elt slot index
      f16x8 af[4], bfr[4];
#pragma unroll
      for (int mi = 0; mi < 4; ++mi)
        af[mi] = *(const f16x8*)(As + (wm + mi * 16 + lrow) * BK + (slot << 3));
#pragma unroll
      for (int ni = 0; ni < 4; ++ni)
        bfr[ni] = *(const f16x8*)(Bs + (wn + ni * 16 + lrow) * BK + (slot << 3));
#pragma unroll
      for (int mi = 0; mi < 4; ++mi)
#pragma unroll
        for (int ni = 0; ni < 4; ++ni)
          acc[mi][ni] = __builtin_amdgcn_mfma_f32_16x16x32_f16(af[mi], bfr[ni],
                                                              acc[mi][ni], 0, 0, 0);
    }
    __syncthreads();
  }
}

// ---------------------------------------------------------------------------
// Kernel 0: fused f32 -> f16 cast for x, Wq, Wk, Wv. 2 rows/block.
__global__ __launch_bounds__(256) void split_all_kernel(
    const float* __restrict__ x, const float* __restrict__ Wq,
    const float* __restrict__ Wk, const float* __restrict__ Wv,
    _Float16* __restrict__ xh, _Float16* __restrict__ Wqh,
    _Float16* __restrict__ Wkh, _Float16* __restrict__ Wvh) {
  const int t = threadIdx.x;
#pragma unroll
  for (int j = 0; j < 2; ++j) {
    int r = blockIdx.x * 2 + j;
    const float* src;
    _Float16* dst;
    if (r < MTOT)            { src = x;  dst = xh;  }
    else if (r < MTOT + DIM) { src = Wq; dst = Wqh; r -= MTOT; }
    else if (r < MTOT + 2 * DIM) { src = Wk; dst = Wkh; r -= MTOT + DIM; }
    else                     { src = Wv; dst = Wvh; r -= MTOT + 2 * DIM; }
    const f32x4 v = ((const f32x4*)(src + (size_t)r * DIM))[t];
    f16x4 hi = {(_Float16)v.x, (_Float16)v.y, (_Float16)v.z, (_Float16)v.w};
    ((f16x4*)(dst + (size_t)r * DIM))[t] = hi;
  }
}

// ---------------------------------------------------------------------------
// Kernel 1: QKV projections, all K=1024 (xh @ Wh^T). 1-D grid, 512 blocks/z.
// Decode: z = l>>9; within z: m = (l&7) + 8*(l>>6), n = (l>>3)&7  (8x8
// super-tiles; XCD = l&7 handles one m-row, B-tiles L2-resident).
__global__ __launch_bounds__(256, 2) void qkv_kernel(
    const _Float16* __restrict__ xh,
    const _Float16* __restrict__ Wqh, const float* __restrict__ bq,
    const _Float16* __restrict__ Wkh, const float* __restrict__ bk,
    const _Float16* __restrict__ Wvh, const float* __restrict__ bv,
    _Float16* __restrict__ Qp, _Float16* __restrict__ Kp,
    _Float16* __restrict__ Vt) {
  __shared__ alignas(16) _Float16 As[BM * BK];
  __shared__ alignas(16) _Float16 Bs[BN * BK];
  f32x4 acc[4][4] = {};
  const int l = blockIdx.x;
  const int z = l >> 9;
  const int r9 = l & 511;
  const int m0 = (((r9 & 7) | ((r9 >> 6) << 3))) * BM;
  const int n0 = ((r9 >> 3) & 7) * BN;
  const _Float16* W = (z == 0) ? Wqh : (z == 1) ? Wkh : Wvh;
  const float* bias = (z == 0) ? bq : (z == 1) ? bk : bv;
  gemm_core(xh, DIM, W, DIM, DIM, m0, n0, As, Bs, acc);

  const int t = threadIdx.x, w = t >> 6, lrow = t & 15, quad = (t >> 4) & 3;
  const int wm = (w >> 1) << 6, wn = (w & 1) << 6;
  if (z == 2) {
    // Vt[b][col][s]: 4 consecutive s per (mi,ni) -> vectorized f16x4 store.
    const int b = m0 >> 11;
    const int s_base = (m0 & (SEQ - 1)) + wm + quad * 4;
#pragma unroll
    for (int ni = 0; ni < 4; ++ni) {
      const int col = n0 + wn + ni * 16 + lrow;
      const float bb = bias[col];
      _Float16* vrow = Vt + (size_t)((b << 10) + col) * SEQ;
#pragma unroll
      for (int mi = 0; mi < 4; ++mi) {
        f16x4 v4 = {(_Float16)(acc[mi][ni][0] + bb),
                    (_Float16)(acc[mi][ni][1] + bb),
                    (_Float16)(acc[mi][ni][2] + bb),
                    (_Float16)(acc[mi][ni][3] + bb)};
        *(f16x4*)(vrow + s_base + mi * 16) = v4;
      }
    }
  } else {
    _Float16* base = (z == 0) ? Qp : Kp;
#pragma unroll
    for (int ni = 0; ni < 4; ++ni) {
      const int col = n0 + wn + ni * 16 + lrow;
      const float bb = bias[col];
#pragma unroll
      for (int mi = 0; mi < 4; ++mi) {
#pragma unroll
        for (int r = 0; r < 4; ++r) {
          const int row = m0 + wm + mi * 16 + quad * 4 + r;
          base[(size_t)row * DIM + col] = (_Float16)(acc[mi][ni][r] + bb);
        }
      }
    }
  }
}

// ---------------------------------------------------------------------------
// Kernel 2: scores[b] = Q[b] @ K[b]^T (K=1024), f32 out (nontemporal).
// 1-D grid, 256 blocks/batch: s=r>>6 picks (m_sup=s&1, n_sup=s>>1).
__global__ __launch_bounds__(256, 2) void scores_kernel(
    const _Float16* __restrict__ Qp, const _Float16* __restrict__ Kp,
    float* __restrict__ Sc) {
  __shared__ alignas(16) _Float16 As[BM * BK];
  __shared__ alignas(16) _Float16 Bs[BN * BK];
  f32x4 acc[4][4] = {};
  const int l = blockIdx.x;
  const int b = l >> 8;
  const int r8 = l & 255;
  const int s = r8 >> 6;
  const int m0 = ((r8 & 7) | ((s & 1) << 3)) * BM;
  const int n0 = (((r8 >> 3) & 7) | ((s >> 1) << 3)) * BN;
  gemm_core(Qp + (size_t)b * SEQ * DIM, DIM,
            Kp + (size_t)b * SEQ * DIM, DIM, DIM, m0, n0, As, Bs, acc);
  float* out = Sc + (size_t)b * SEQ * SEQ;
  const int t = threadIdx.x, w = t >> 6, lrow = t & 15, quad = (t >> 4) & 3;
  const int wm = (w >> 1) << 6, wn = (w & 1) << 6;
#pragma unroll
  for (int ni = 0; ni < 4; ++ni) {
    const int col = n0 + wn + ni * 16 + lrow;
#pragma unroll
    for (int mi = 0; mi < 4; ++mi) {
#pragma unroll
      for (int r = 0; r < 4; ++r) {
        const int row = m0 + wm + mi * 16 + quad * 4 + r;
        __builtin_nontemporal_store(acc[mi][ni][r],
                                    out + (size_t)row * SEQ + col);
      }
    }
  }
}

// ---------------------------------------------------------------------------
// Kernel 3: row softmax, 4 rows/block, P = softmax(S)*(1/32), f16 out.
// Sc loads nontemporal (zero reuse).
__global__ __launch_bounds__(256) void softmax_kernel(const float* __restrict__ Sc,
                                                      _Float16* __restrict__ P) {
  const int r0 = blockIdx.x * 4;
  const int t = threadIdx.x;
  const int w = t >> 6;
  __shared__ float red[32];

  f32x4 v[4][2];
  float m[4], sum[4];
#pragma unroll
  for (int j = 0; j < 4; ++j) {
    const f32x4* row = (const f32x4*)(Sc + (size_t)(r0 + j) * SEQ);
    v[j][0] = __builtin_nontemporal_load(row + t);
    v[j][1] = __builtin_nontemporal_load(row + t + 256);
  }
#pragma unroll
  for (int j = 0; j < 4; ++j) {
    m[j] = fmaxf(fmaxf(fmaxf(v[j][0].x, v[j][0].y), fmaxf(v[j][0].z, v[j][0].w)),
                 fmaxf(fmaxf(v[j][1].x, v[j][1].y), fmaxf(v[j][1].z, v[j][1].w)));
  }
#pragma unroll
  for (int o = 32; o; o >>= 1)
#pragma unroll
    for (int j = 0; j < 4; ++j) m[j] = fmaxf(m[j], __shfl_down(m[j], o));
  if ((t & 63) == 0) {
#pragma unroll
    for (int j = 0; j < 4; ++j) red[j * 4 + w] = m[j];
  }
  __syncthreads();
#pragma unroll
  for (int j = 0; j < 4; ++j)
    m[j] = fmaxf(fmaxf(red[j * 4], red[j * 4 + 1]),
                 fmaxf(red[j * 4 + 2], red[j * 4 + 3]));

  float e[4][8];
#pragma unroll
  for (int j = 0; j < 4; ++j) {
    e[j][0] = __expf(v[j][0].x - m[j]); e[j][1] = __expf(v[j][0].y - m[j]);
    e[j][2] = __expf(v[j][0].z - m[j]); e[j][3] = __expf(v[j][0].w - m[j]);
    e[j][4] = __expf(v[j][1].x - m[j]); e[j][5] = __expf(v[j][1].y - m[j]);
    e[j][6] = __expf(v[j][1].z - m[j]); e[j][7] = __expf(v[j][1].w - m[j]);
    sum[j] = ((e[j][0] + e[j][1]) + (e[j][2] + e[j][3])) +
             ((e[j][4] + e[j][5]) + (e[j][6] + e[j][7]));
  }
#pragma unroll
  for (int o = 32; o; o >>= 1)
#pragma unroll
    for (int j = 0; j < 4; ++j) sum[j] += __shfl_down(sum[j], o);
  if ((t & 63) == 0) {
#pragma unroll
    for (int j = 0; j < 4; ++j) red[16 + j * 4 + w] = sum[j];
  }
  __syncthreads();
#pragma unroll
  for (int j = 0; j < 4; ++j) {
    const float s = (red[16 + j * 4] + red[16 + j * 4 + 1]) +
                    (red[16 + j * 4 + 2] + red[16 + j * 4 + 3]);
    const float sc = 0.03125f / s;  // post-softmax 1/sqrt(Dk)=1/32 folded in
    _Float16* prow = P + (size_t)(r0 + j) * SEQ;
    f16x4 o1 = {(_Float16)(e[j][0] * sc), (_Float16)(e[j][1] * sc),
                (_Float16)(e[j][2] * sc), (_Float16)(e[j][3] * sc)};
    f16x4 o2 = {(_Float16)(e[j][4] * sc), (_Float16)(e[j][5] * sc),
                (_Float16)(e[j][6] * sc), (_Float16)(e[j][7] * sc)};
    ((f16x4*)prow)[t] = o1;
    ((f16x4*)prow)[t + 256] = o2;
  }
}

// ---------------------------------------------------------------------------
// Kernel 4: O[b] = P[b] @ V[b]  (Vt [v][s] -> B^T GEMM, K=2048), f32 out (nt).
// 1-D grid, 128 blocks/batch: m=(r&7)+8*(r>>6), n=(r>>3)&7.
__global__ __launch_bounds__(256, 2) void pv_kernel(
    const _Float16* __restrict__ P, const _Float16* __restrict__ Vt,
    float* __restrict__ out) {
  __shared__ alignas(16) _Float16 As[BM * BK];
  __shared__ alignas(16) _Float16 Bs[BN * BK];
  f32x4 acc[4][4] = {};
  const int l = blockIdx.x;
  const int b = l >> 7;
  const int r7 = l & 127;
  const int m0 = ((r7 & 7) | ((r7 >> 6) << 3)) * BM;
  const int n0 = ((r7 >> 3) & 7) * BN;
  gemm_core(P + (size_t)b * SEQ * SEQ, SEQ,
            Vt + (size_t)b * DIM * SEQ, SEQ, SEQ, m0, n0, As, Bs, acc);
  float* ob = out + (size_t)b * SEQ * DIM;
  const int t = threadIdx.x, w = t >> 6, lrow = t & 15, quad = (t >> 4) & 3;
  const int wm = (w >> 1) << 6, wn = (w & 1) << 6;
#pragma unroll
  for (int ni = 0; ni < 4; ++ni) {
    const int col = n0 + wn + ni * 16 + lrow;
#pragma unroll
    for (int mi = 0; mi < 4; ++mi) {
#pragma unroll
      for (int r = 0; r < 4; ++r) {
        const int row = m0 + wm + mi * 16 + quad * 4 + r;
        __builtin_nontemporal_store(acc[mi][ni][r],
                                    ob + (size_t)row * DIM + col);
      }
    }
  }
}

// ---------------------------------------------------------------------------
extern "C" void kernel_launch(void* const* d_in, const int* in_sizes, int n_in,
                              void* d_out, int out_size, void* d_ws, size_t ws_size,
                              hipStream_t stream) {
  const float* x  = (const float*)d_in[0];
  const float* Wq = (const float*)d_in[1];
  const float* bq = (const float*)d_in[2];
  const float* Wk = (const float*)d_in[3];
  const float* bk = (const float*)d_in[4];
  const float* Wv = (const float*)d_in[5];
  const float* bv = (const float*)d_in[6];
  float* out = (float*)d_out;  // reference output dtype is float32

  char* ws = (char*)d_ws;
  _Float16* Qp  = (_Float16*)(ws);                 // 16 MB [8192][1024]
  _Float16* Kp  = (_Float16*)(ws + 16777216);      // 16 MB
  _Float16* Vt  = (_Float16*)(ws + 33554432);      // 16 MB [4][1024][2048]
  float*    Sc  = (float*)(ws + 50331648);         // 64 MB [4][2048][2048] f32
  _Float16* P   = (_Float16*)(ws + 117440512);     // 32 MB [4][2048][2048] f16
  // xh + W hi planes alias the Sc region (dead once scores_kernel runs):
  _Float16* xh  = (_Float16*)(ws + 50331648);      // 16 MB [8192][1024]
  _Float16* Wqh = (_Float16*)(ws + 67108864);      //  2 MB
  _Float16* Wkh = (_Float16*)(ws + 69206016);      //  2 MB
  _Float16* Wvh = (_Float16*)(ws + 71303168);      //  2 MB
  // peak 150,994,944 B

  dim3 blk(256, 1, 1);
  split_all_kernel<<<dim3((MTOT + 3 * DIM) / 2), blk, 0, stream>>>(
      x, Wq, Wk, Wv, xh, Wqh, Wkh, Wvh);
  qkv_kernel<<<dim3(3 * 512), blk, 0, stream>>>(
      xh, Wqh, bq, Wkh, bk, Wvh, bv, Qp, Kp, Vt);
  scores_kernel<<<dim3(NBATCH * 256), blk, 0, stream>>>(Qp, Kp, Sc);
  softmax_kernel<<<dim3(MTOT / 4), blk, 0, stream>>>(Sc, P);
  pv_kernel<<<dim3(NBATCH * 128), blk, 0, stream>>>(P, Vt, out);
}